// Round 1
// baseline (570.814 us; speedup 1.0000x reference)
//
#include <hip/hip_runtime.h>

#define BATCH 512
#define DIM 64
#define KOUT 63

typedef float vf4 __attribute__((ext_vector_type(4)));

// ---------------------------------------------------------------------------
// Kernel 1: bilinear stage (unchanged — ~15-20 us, not the bottleneck).
// grid = dim3(192, 2): blockIdx.x = which*64 + k (k in [0,64)), blockIdx.y = batch half.
// block = 256 threads, 1 batch per thread.
// o[which][b][k] = sum_ij A[b,i] * W[k,i,j] * C[b,j] + bias[k];  o[..][63] = 1.0
// W[k] (16 KiB) staged in LDS once per block, reused by 256 batches.
// ---------------------------------------------------------------------------
__global__ __launch_bounds__(256) void bilinear_kernel(
    const float* __restrict__ x, const float* __restrict__ y, const float* __restrict__ z,
    const float* __restrict__ W1, const float* __restrict__ b1,
    const float* __restrict__ W2, const float* __restrict__ b2,
    const float* __restrict__ W3, const float* __restrict__ b3,
    float* __restrict__ o /* [3][512][64] */) {
    const int which = blockIdx.x >> 6;
    const int k     = blockIdx.x & 63;
    const int b     = blockIdx.y * 256 + threadIdx.x;

    float* outp = o + which * (BATCH * DIM);

    if (k == KOUT) {            // ones column — uniform across block, no divergence
        outp[b * DIM + KOUT] = 1.0f;
        return;
    }

    const float* A  = (which == 2) ? y : x;
    const float* C  = (which == 0) ? y : z;
    const float* W  = ((which == 0) ? W1 : (which == 1) ? W2 : W3) + k * (DIM * DIM);
    const float  bias = ((which == 0) ? b1 : (which == 1) ? b2 : b3)[k];

    __shared__ float sW[DIM * DIM];
    {
        const float4* W4  = (const float4*)W;
        float4*       sW4 = (float4*)sW;
        #pragma unroll
        for (int t = threadIdx.x; t < DIM * DIM / 4; t += 256) sW4[t] = W4[t];
    }
    __syncthreads();

    // y-side row in registers (inner loop fully unrolled -> constant indices)
    float c[DIM];
    {
        const float4* C4 = (const float4*)(C + b * DIM);
        #pragma unroll
        for (int q = 0; q < DIM / 4; q++) {
            float4 v = C4[q];
            c[4 * q + 0] = v.x; c[4 * q + 1] = v.y; c[4 * q + 2] = v.z; c[4 * q + 3] = v.w;
        }
    }

    const float* arow = A + b * DIM;
    const float4* sW4 = (const float4*)sW;
    float acc = bias;
    #pragma unroll 4
    for (int i = 0; i < DIM; i++) {
        float t = 0.0f;
        #pragma unroll
        for (int q = 0; q < DIM / 4; q++) {
            float4 w = sW4[i * (DIM / 4) + q];   // ds_read_b128, wave-uniform broadcast
            t = fmaf(w.x, c[4 * q + 0], t);
            t = fmaf(w.y, c[4 * q + 1], t);
            t = fmaf(w.z, c[4 * q + 2], t);
            t = fmaf(w.w, c[4 * q + 3], t);
        }
        acc = fmaf(arow[i], t, acc);
    }
    outp[b * DIM + k] = acc;
}

// ---------------------------------------------------------------------------
// Kernel 2: triple outer product, 512 MiB streaming write.
// REWORKED: grid = dim3(512, 16). blockIdx.x = batch, blockIdx.y = i-segment
// (i in [seg*4, seg*4+4)). 8192 blocks (vs 512): up to 8 resident blocks/CU,
// 32 waves/CU — enough TLP to saturate the nontemporal write path (the
// harness fill kernel proves ~6.3 TB/s is reachable; the old 2-blocks/CU
// launch ran at ~2.5 TB/s).
//
// Per-thread mapping (t = threadIdx.x, it = 0..15, f4 = seg*4096 + it*256 + t):
//   k4 = f4 & 15        = t & 15            -> constant: hoist v3
//   j  = (f4 >> 4) & 63 = (t>>4) + 16*(it&3)-> 4 distinct values
//   i  = f4 >> 10       = seg*4  + (it>>2)  -> 4 distinct values
// All 16 s1[i]*s2[j] products precomputed in registers with static indices;
// the store loop is pure independent global_store_dwordx4 nt.
// ---------------------------------------------------------------------------
__global__ __launch_bounds__(256) void outer_kernel(
    const float* __restrict__ o /* [3][512][64] */, float* __restrict__ out) {
    const int b   = blockIdx.x;
    const int seg = blockIdx.y;

    __shared__ float s1[4];
    __shared__ float s2[DIM];
    __shared__ float s3f[DIM];

    const int t = threadIdx.x;
    if (t < 64)        s2[t]        = o[BATCH * DIM + b * DIM + t];
    else if (t < 128)  s3f[t - 64]  = o[2 * BATCH * DIM + b * DIM + (t - 64)];
    else if (t < 132)  s1[t - 128]  = o[b * DIM + seg * 4 + (t - 128)];
    __syncthreads();

    const vf4 v3 = ((const vf4*)s3f)[t & 15];   // constant per thread
    const int jb = t >> 4;                       // 0..15

    float p[4][4];                               // [i_local][j_cycle], static indexing only
    #pragma unroll
    for (int ii = 0; ii < 4; ++ii) {
        const float a = s1[ii];
        #pragma unroll
        for (int jc = 0; jc < 4; ++jc) p[ii][jc] = a * s2[jb + 16 * jc];
    }

    vf4* out4 = (vf4*)out + (size_t)b * 65536 + seg * 4096 + t;
    #pragma unroll
    for (int it = 0; it < 16; ++it) {
        vf4 v = v3 * p[it >> 2][it & 3];
        __builtin_nontemporal_store(v, &out4[it * 256]);
    }
}

extern "C" void kernel_launch(void* const* d_in, const int* in_sizes, int n_in,
                              void* d_out, int out_size, void* d_ws, size_t ws_size,
                              hipStream_t stream) {
    const float* x  = (const float*)d_in[0];
    const float* y  = (const float*)d_in[1];
    const float* z  = (const float*)d_in[2];
    const float* W1 = (const float*)d_in[3];
    const float* b1 = (const float*)d_in[4];
    const float* W2 = (const float*)d_in[5];
    const float* b2 = (const float*)d_in[6];
    const float* W3 = (const float*)d_in[7];
    const float* b3 = (const float*)d_in[8];
    float* out = (float*)d_out;
    float* o   = (float*)d_ws;   // [3][512][64] = 384 KiB

    bilinear_kernel<<<dim3(192, 2), 256, 0, stream>>>(x, y, z, W1, b1, W2, b2, W3, b3, o);
    outer_kernel<<<dim3(BATCH, 16), 256, 0, stream>>>(o, out);
}

// Round 2
// 559.036 us; speedup vs baseline: 1.0211x; 1.0211x over previous
//
#include <hip/hip_runtime.h>

#define BATCH 512
#define DIM 64
#define KOUT 63

typedef float vf4 __attribute__((ext_vector_type(4)));

// ---------------------------------------------------------------------------
// Kernel 1: bilinear stage (unchanged — ~15-20 us, not the bottleneck).
// grid = dim3(192, 2): blockIdx.x = which*64 + k (k in [0,64)), blockIdx.y = batch half.
// block = 256 threads, 1 batch per thread.
// o[which][b][k] = sum_ij A[b,i] * W[k,i,j] * C[b,j] + bias[k];  o[..][63] = 1.0
// W[k] (16 KiB) staged in LDS once per block, reused by 256 batches.
// ---------------------------------------------------------------------------
__global__ __launch_bounds__(256) void bilinear_kernel(
    const float* __restrict__ x, const float* __restrict__ y, const float* __restrict__ z,
    const float* __restrict__ W1, const float* __restrict__ b1,
    const float* __restrict__ W2, const float* __restrict__ b2,
    const float* __restrict__ W3, const float* __restrict__ b3,
    float* __restrict__ o /* [3][512][64] */) {
    const int which = blockIdx.x >> 6;
    const int k     = blockIdx.x & 63;
    const int b     = blockIdx.y * 256 + threadIdx.x;

    float* outp = o + which * (BATCH * DIM);

    if (k == KOUT) {            // ones column — uniform across block, no divergence
        outp[b * DIM + KOUT] = 1.0f;
        return;
    }

    const float* A  = (which == 2) ? y : x;
    const float* C  = (which == 0) ? y : z;
    const float* W  = ((which == 0) ? W1 : (which == 1) ? W2 : W3) + k * (DIM * DIM);
    const float  bias = ((which == 0) ? b1 : (which == 1) ? b2 : b3)[k];

    __shared__ float sW[DIM * DIM];
    {
        const float4* W4  = (const float4*)W;
        float4*       sW4 = (float4*)sW;
        #pragma unroll
        for (int t = threadIdx.x; t < DIM * DIM / 4; t += 256) sW4[t] = W4[t];
    }
    __syncthreads();

    // y-side row in registers (inner loop fully unrolled -> constant indices)
    float c[DIM];
    {
        const float4* C4 = (const float4*)(C + b * DIM);
        #pragma unroll
        for (int q = 0; q < DIM / 4; q++) {
            float4 v = C4[q];
            c[4 * q + 0] = v.x; c[4 * q + 1] = v.y; c[4 * q + 2] = v.z; c[4 * q + 3] = v.w;
        }
    }

    const float* arow = A + b * DIM;
    const float4* sW4 = (const float4*)sW;
    float acc = bias;
    #pragma unroll 4
    for (int i = 0; i < DIM; i++) {
        float t = 0.0f;
        #pragma unroll
        for (int q = 0; q < DIM / 4; q++) {
            float4 w = sW4[i * (DIM / 4) + q];   // ds_read_b128, wave-uniform broadcast
            t = fmaf(w.x, c[4 * q + 0], t);
            t = fmaf(w.y, c[4 * q + 1], t);
            t = fmaf(w.z, c[4 * q + 2], t);
            t = fmaf(w.w, c[4 * q + 3], t);
        }
        acc = fmaf(arow[i], t, acc);
    }
    outp[b * DIM + k] = acc;
}

// ---------------------------------------------------------------------------
// Kernel 2: triple outer product, 512 MiB streaming write.
// Round-2 A/B: REGULAR stores instead of __builtin_nontemporal_store.
// The harness fill kernel hits 6.2 TB/s with regular stores; round-1 showed
// occupancy (2 vs 8 blocks/CU) is NOT the limiter, so the nt cache-bypass
// path is the remaining suspect for the outer kernel's gap above its
// 536MB/6.3TBps = 86 us floor. Output >> L2 so eviction bytes are identical.
//
// grid = dim3(512, 16). blockIdx.x = batch, blockIdx.y = i-segment.
// Per-thread mapping (t = threadIdx.x, it = 0..15, f4 = seg*4096 + it*256 + t):
//   k4 = t & 15 (constant -> hoist v3); j = (t>>4) + 16*(it&3); i = seg*4 + (it>>2)
// All 16 s1[i]*s2[j] products precomputed in registers, statically indexed;
// store loop is pure independent global_store_dwordx4.
// ---------------------------------------------------------------------------
__global__ __launch_bounds__(256) void outer_kernel(
    const float* __restrict__ o /* [3][512][64] */, float* __restrict__ out) {
    const int b   = blockIdx.x;
    const int seg = blockIdx.y;

    __shared__ float s1[4];
    __shared__ float s2[DIM];
    __shared__ float s3f[DIM];

    const int t = threadIdx.x;
    if (t < 64)        s2[t]        = o[BATCH * DIM + b * DIM + t];
    else if (t < 128)  s3f[t - 64]  = o[2 * BATCH * DIM + b * DIM + (t - 64)];
    else if (t < 132)  s1[t - 128]  = o[b * DIM + seg * 4 + (t - 128)];
    __syncthreads();

    const vf4 v3 = ((const vf4*)s3f)[t & 15];   // constant per thread
    const int jb = t >> 4;                       // 0..15

    float p[4][4];                               // [i_local][j_cycle], static indexing only
    #pragma unroll
    for (int ii = 0; ii < 4; ++ii) {
        const float a = s1[ii];
        #pragma unroll
        for (int jc = 0; jc < 4; ++jc) p[ii][jc] = a * s2[jb + 16 * jc];
    }

    vf4* out4 = (vf4*)out + (size_t)b * 65536 + seg * 4096 + t;
    #pragma unroll
    for (int it = 0; it < 16; ++it) {
        out4[it * 256] = v3 * p[it >> 2][it & 3];   // regular global_store_dwordx4
    }
}

extern "C" void kernel_launch(void* const* d_in, const int* in_sizes, int n_in,
                              void* d_out, int out_size, void* d_ws, size_t ws_size,
                              hipStream_t stream) {
    const float* x  = (const float*)d_in[0];
    const float* y  = (const float*)d_in[1];
    const float* z  = (const float*)d_in[2];
    const float* W1 = (const float*)d_in[3];
    const float* b1 = (const float*)d_in[4];
    const float* W2 = (const float*)d_in[5];
    const float* b2 = (const float*)d_in[6];
    const float* W3 = (const float*)d_in[7];
    const float* b3 = (const float*)d_in[8];
    float* out = (float*)d_out;
    float* o   = (float*)d_ws;   // [3][512][64] = 384 KiB

    bilinear_kernel<<<dim3(192, 2), 256, 0, stream>>>(x, y, z, W1, b1, W2, b2, W3, b3, o);
    outer_kernel<<<dim3(BATCH, 16), 256, 0, stream>>>(o, out);
}

// Round 3
// 558.819 us; speedup vs baseline: 1.0215x; 1.0004x over previous
//
#include <hip/hip_runtime.h>

#define BATCH 512
#define DIM 64
#define KOUT 63

typedef float vf4 __attribute__((ext_vector_type(4)));

// ---------------------------------------------------------------------------
// Kernel 1: bilinear stage (unchanged).
// ---------------------------------------------------------------------------
__global__ __launch_bounds__(256) void bilinear_kernel(
    const float* __restrict__ x, const float* __restrict__ y, const float* __restrict__ z,
    const float* __restrict__ W1, const float* __restrict__ b1,
    const float* __restrict__ W2, const float* __restrict__ b2,
    const float* __restrict__ W3, const float* __restrict__ b3,
    float* __restrict__ o /* [3][512][64] */) {
    const int which = blockIdx.x >> 6;
    const int k     = blockIdx.x & 63;
    const int b     = blockIdx.y * 256 + threadIdx.x;

    float* outp = o + which * (BATCH * DIM);

    if (k == KOUT) {            // ones column — uniform across block, no divergence
        outp[b * DIM + KOUT] = 1.0f;
        return;
    }

    const float* A  = (which == 2) ? y : x;
    const float* C  = (which == 0) ? y : z;
    const float* W  = ((which == 0) ? W1 : (which == 1) ? W2 : W3) + k * (DIM * DIM);
    const float  bias = ((which == 0) ? b1 : (which == 1) ? b2 : b3)[k];

    __shared__ float sW[DIM * DIM];
    {
        const float4* W4  = (const float4*)W;
        float4*       sW4 = (float4*)sW;
        #pragma unroll
        for (int t = threadIdx.x; t < DIM * DIM / 4; t += 256) sW4[t] = W4[t];
    }
    __syncthreads();

    float c[DIM];
    {
        const float4* C4 = (const float4*)(C + b * DIM);
        #pragma unroll
        for (int q = 0; q < DIM / 4; q++) {
            float4 v = C4[q];
            c[4 * q + 0] = v.x; c[4 * q + 1] = v.y; c[4 * q + 2] = v.z; c[4 * q + 3] = v.w;
        }
    }

    const float* arow = A + b * DIM;
    const float4* sW4 = (const float4*)sW;
    float acc = bias;
    #pragma unroll 4
    for (int i = 0; i < DIM; i++) {
        float t = 0.0f;
        #pragma unroll
        for (int q = 0; q < DIM / 4; q++) {
            float4 w = sW4[i * (DIM / 4) + q];   // ds_read_b128, wave-uniform broadcast
            t = fmaf(w.x, c[4 * q + 0], t);
            t = fmaf(w.y, c[4 * q + 1], t);
            t = fmaf(w.z, c[4 * q + 2], t);
            t = fmaf(w.w, c[4 * q + 3], t);
        }
        acc = fmaf(arow[i], t, acc);
    }
    outp[b * DIM + k] = acc;
}

// ---------------------------------------------------------------------------
// Kernel 2: DIAGNOSTIC ROUND — triple outer product written TWICE.
// Identical values both passes (idempotent -> output correct); asm memory
// clobber prevents dead-store elimination of pass 1. Purpose: measure the
// outer kernel's achieved write bandwidth, which is invisible in the top-5
// (all fills are >=339 us, outer is 90-190 us).
//   Branch A (outer at ~6.2 TB/s): dur_us ~= 559 + 86 = ~645, outer (~172us)
//     still absent from top-5 -> outer was at roofline; revert & declare.
//   Branch B (outer at ~2.8 TB/s): dur_us ~= 750 and outer (~380us) ENTERS
//     the top-5 with hbm_gbps/WRITE_SIZE directly readable -> dig.
// ---------------------------------------------------------------------------
__global__ __launch_bounds__(256) void outer_kernel(
    const float* __restrict__ o /* [3][512][64] */, float* __restrict__ out) {
    const int b   = blockIdx.x;
    const int seg = blockIdx.y;

    __shared__ float s1[4];
    __shared__ float s2[DIM];
    __shared__ float s3f[DIM];

    const int t = threadIdx.x;
    if (t < 64)        s2[t]        = o[BATCH * DIM + b * DIM + t];
    else if (t < 128)  s3f[t - 64]  = o[2 * BATCH * DIM + b * DIM + (t - 64)];
    else if (t < 132)  s1[t - 128]  = o[b * DIM + seg * 4 + (t - 128)];
    __syncthreads();

    const vf4 v3 = ((const vf4*)s3f)[t & 15];   // constant per thread
    const int jb = t >> 4;                       // 0..15

    float p[4][4];                               // [i_local][j_cycle], static indexing only
    #pragma unroll
    for (int ii = 0; ii < 4; ++ii) {
        const float a = s1[ii];
        #pragma unroll
        for (int jc = 0; jc < 4; ++jc) p[ii][jc] = a * s2[jb + 16 * jc];
    }

    vf4* out4 = (vf4*)out + (size_t)b * 65536 + seg * 4096 + t;

    // pass 1
    #pragma unroll
    for (int it = 0; it < 16; ++it) {
        out4[it * 256] = v3 * p[it >> 2][it & 3];
    }
    asm volatile("" ::: "memory");   // keep pass 1's stores live
    // pass 2 (identical values, same addresses)
    #pragma unroll
    for (int it = 0; it < 16; ++it) {
        out4[it * 256] = v3 * p[it >> 2][it & 3];
    }
}

extern "C" void kernel_launch(void* const* d_in, const int* in_sizes, int n_in,
                              void* d_out, int out_size, void* d_ws, size_t ws_size,
                              hipStream_t stream) {
    const float* x  = (const float*)d_in[0];
    const float* y  = (const float*)d_in[1];
    const float* z  = (const float*)d_in[2];
    const float* W1 = (const float*)d_in[3];
    const float* b1 = (const float*)d_in[4];
    const float* W2 = (const float*)d_in[5];
    const float* b2 = (const float*)d_in[6];
    const float* W3 = (const float*)d_in[7];
    const float* b3 = (const float*)d_in[8];
    float* out = (float*)d_out;
    float* o   = (float*)d_ws;   // [3][512][64] = 384 KiB

    bilinear_kernel<<<dim3(192, 2), 256, 0, stream>>>(x, y, z, W1, b1, W2, b2, W3, b3, o);
    outer_kernel<<<dim3(BATCH, 16), 256, 0, stream>>>(o, out);
}